// Round 12
// baseline (203.770 us; speedup 1.0000x reference)
//
#include <hip/hip_runtime.h>

// Viterbi decoder forward: B=32, T=256, L=48, START=46, END=47.
// R12 = R11 (pinned register prefetch, 4 waves x 12 i's, lane j = label,
// LDS partial merge, inline argmax, prob-domain LSE) with the per-step
// s_barrier REPLACED by a tag-based LDS flag protocol:
//   each wave: write partials (parity slot) -> fence -> lane0 writes
//   volatile tag = t; consumers poll the 4 tags (uniform broadcast
//   reads) until == t, fence, then read partials. Per-wave DS ordering
//   gives data-before-tag; the parity double-buffer provably prevents
//   WAR across steps. Tags are exact ints -> deterministic.

#define TT 256
#define LL 48
#define ROWF 2304          // 48*48 floats per time-row
#define LSTART 46
#define LEND 47
#define BB 32
#define LOG2E 1.44269504088896f
#define LN2 0.693147180559945f

#define RL(var, lane) __int_as_float(__builtin_amdgcn_readlane(__float_as_int(var), (lane)))

// keep-alive pin: forces the 12 loaded values live HERE; compiler puts
// its counted vmcnt wait at the pin (off the critical chain).
#define PIN12(B) asm volatile("" : \
    "+v"((B)[0]), "+v"((B)[1]), "+v"((B)[2]),  "+v"((B)[3]), \
    "+v"((B)[4]), "+v"((B)[5]), "+v"((B)[6]),  "+v"((B)[7]), \
    "+v"((B)[8]), "+v"((B)[9]), "+v"((B)[10]), "+v"((B)[11]))

// plain (compiler-managed) load of this lane's 12-element slice of ROW
#define LOADROW(B, ROW) do { \
    const float* q_ = emB + (size_t)(ROW)*ROWF + (size_t)(12*w)*LL + jl; \
    _Pragma("unroll") \
    for (int k = 0; k < 12; ++k) (B)[k] = q_[k*LL]; \
  } while (0)

// strict > with ordered pairing == jnp.argmax first-occurrence semantics
#define AMAX(vx, ix, vy, iy) do { if ((vy) > (vx)) { (vx)=(vy); (ix)=(iy);} } while(0)

// ---- flag-sync primitives ----
// publish: data store (already issued) -> compiler fence -> volatile tag
#define PUBLISH(TAGARR, PW, TG) do { \
    asm volatile("" ::: "memory"); \
    if ((tid & 63) == 0) *(volatile int*)&TAGARR[PW][w] = (TG); \
  } while (0)
// poll all 4 wave tags of slot PR for value TG (uniform broadcast reads)
#define POLL(TAGARR, PR, TG) do { \
    volatile int* vt_ = &TAGARR[PR][0]; \
    while ((vt_[0] ^ (TG)) | (vt_[1] ^ (TG)) | (vt_[2] ^ (TG)) | (vt_[3] ^ (TG))) {} \
    asm volatile("" ::: "memory"); \
  } while (0)

// 12-candidate partial max/argmax tree -> partV[PW][w][j]
#define PARTIALS_V(ETR, PW) do { \
    float cv[12]; int ci[12]; \
    _Pragma("unroll") \
    for (int k = 0; k < 12; ++k) { \
      cv[k] = (ETR)[k] + RL(vbest, 12*w + k); ci[k] = 12*w + k; } \
    AMAX(cv[0],ci[0],cv[1],ci[1]);  AMAX(cv[2],ci[2],cv[3],ci[3]); \
    AMAX(cv[4],ci[4],cv[5],ci[5]);  AMAX(cv[6],ci[6],cv[7],ci[7]); \
    AMAX(cv[8],ci[8],cv[9],ci[9]);  AMAX(cv[10],ci[10],cv[11],ci[11]); \
    AMAX(cv[0],ci[0],cv[2],ci[2]);  AMAX(cv[4],ci[4],cv[6],ci[6]); \
    AMAX(cv[8],ci[8],cv[10],ci[10]); \
    AMAX(cv[0],ci[0],cv[4],ci[4]); \
    AMAX(cv[0],ci[0],cv[8],ci[8]); \
    partV[PW][w][j] = make_float2(cv[0], __int_as_float(ci[0])); \
  } while (0)

#define MERGE_V(T_) do { \
    POLL(tagV, ((T_)) & 1, (T_)); \
    float2 m0_ = partV[(T_)&1][0][j], m1_ = partV[(T_)&1][1][j]; \
    float2 m2_ = partV[(T_)&1][2][j], m3_ = partV[(T_)&1][3][j]; \
    float bv_ = m0_.x; int ba_ = __float_as_int(m0_.y); \
    AMAX(bv_, ba_, m1_.x, __float_as_int(m1_.y)); \
    AMAX(bv_, ba_, m2_.x, __float_as_int(m2_.y)); \
    AMAX(bv_, ba_, m3_.x, __float_as_int(m3_.y)); \
    const bool upd_ = act && ((T_) < len); \
    vbest = upd_ ? bv_ : vbest; \
    if (w == 0 && upd_) bp[(T_)*LL + j] = (unsigned char)ba_; \
  } while (0)

// iteration t: issue row t+3, pin row t+1 (build ETRN off-chain),
// poll+merge step t-1, compute+publish partials of step t.
#define ITER_V(T_, BISS, BPIN, ETRC, ETRN) do { \
    { int row_ = (T_) + 3; if (row_ > 255) row_ = 255; LOADROW(BISS, row_); } \
    PIN12(BPIN); \
    _Pragma("unroll") \
    for (int k = 0; k < 12; ++k) (ETRN)[k] = (BPIN)[k] + trg[k]; \
    MERGE_V((T_)-1); \
    PARTIALS_V(ETRC, (T_) & 1); \
    PUBLISH(tagV, (T_) & 1, T_); \
  } while (0)

#define PARTIALS_L(EE, PW) do { \
    float a0 = 0.f, a1 = 0.f, a2 = 0.f, a3 = 0.f; \
    _Pragma("unroll") \
    for (int k = 0; k < 12; k += 4) { \
      a0 = fmaf((EE)[k+0], RL(P, 12*w + k + 0), a0); \
      a1 = fmaf((EE)[k+1], RL(P, 12*w + k + 1), a1); \
      a2 = fmaf((EE)[k+2], RL(P, 12*w + k + 2), a2); \
      a3 = fmaf((EE)[k+3], RL(P, 12*w + k + 3), a3); \
    } \
    partS[PW][w][j] = (a0 + a1) + (a2 + a3); \
  } while (0)

#define MERGE_L(T_) do { \
    POLL(tagS, ((T_)) & 1, (T_)); \
    float Pn_ = (partS[(T_)&1][0][j] + partS[(T_)&1][1][j]) \
              + (partS[(T_)&1][2][j] + partS[(T_)&1][3][j]); \
    int rb_ = __builtin_amdgcn_readlane(__float_as_int(Pn_), 0); \
    int e_ = ((rb_ >> 23) & 255) - 127; \
    const bool upd_ = ((T_) < len); \
    P    = upd_ ? __builtin_ldexpf(Pn_, -e_) : P; \
    macc = upd_ ? macc + (float)e_ : macc; \
  } while (0)

#define ITER_L(T_, BISS, BPIN, EEC, EEN) do { \
    { int row_ = (T_) + 3; if (row_ > 255) row_ = 255; LOADROW(BISS, row_); } \
    PIN12(BPIN); \
    _Pragma("unroll") \
    for (int k = 0; k < 12; ++k) \
      (EEN)[k] = exp2f(fmaf((BPIN)[k], LOG2E, trg2[k])); \
    MERGE_L((T_)-1); \
    PARTIALS_L(EEC, (T_) & 1); \
    PUBLISH(tagS, (T_) & 1, T_); \
  } while (0)

__device__ __forceinline__ int load_len(const int* len_raw, int b) {
  // lengths int32-or-int64 detection (values 128..256)
  bool is64 = (len_raw[1] == 0) && (len_raw[3] == 0) && (len_raw[5] == 0);
  int len = is64 ? len_raw[2*b] : len_raw[b];
  if (len > TT) len = TT;
  if (len < 1) len = 1;
  return len;
}

__launch_bounds__(256, 1)
__global__ void viterbi_fwd(const float* __restrict__ em,
                            const float* __restrict__ tr,
                            const int* __restrict__ len_raw,
                            float* __restrict__ out,
                            float* __restrict__ ws)
{
  const int role = blockIdx.x >> 5;   // 0 = Viterbi, 1 = LSE
  const int b    = blockIdx.x & 31;
  const int tid  = threadIdx.x;
  const int w    = tid >> 6;
  const int j    = tid & 63;
  const bool act = (j < LL);
  const int jl   = act ? j : (LL - 1);
  const int len  = load_len(len_raw, b);

  __shared__ float2 partV[2][4][64];
  __shared__ float  partS[2][4][64];
  __shared__ int    tagV[2][4];
  __shared__ int    tagS[2][4];
  __shared__ unsigned char bp[TT*LL];
  __shared__ unsigned char cmp_[16*LL];
  __shared__ unsigned char entry_[16];
  __shared__ unsigned char raw[TT];

  const float* emB = em + (size_t)b*TT*ROWF;

  if (role == 0) {
    // ===================== Viterbi =====================
    if ((tid & 63) == 0) {                 // tag init (kills stale LDS)
      *(volatile int*)&tagV[0][w] = -1;
      *(volatile int*)&tagV[1][w] = -1;
    }
    for (int idx = tid; idx < LL; idx += 256) bp[idx] = (unsigned char)LSTART;
    for (int idx = len*LL + tid; idx < TT*LL; idx += 256) bp[idx] = (unsigned char)LEND;
    __syncthreads();

    float trg[12];
    #pragma unroll
    for (int k = 0; k < 12; ++k) trg[k] = tr[(12*w + k)*LL + jl];
    const float init = emB[LSTART*LL + jl] + tr[LSTART*LL + jl];
    float vbest = act ? init : -INFINITY;

    float B0[12], B1[12], B2[12], B3[12], etrA[12], etrB[12];
    // prologue: rows 1..3; partials of step 1 (tag 1); row 4; etrA = row 2
    LOADROW(B1, 1); LOADROW(B2, 2); LOADROW(B3, 3);
    PIN12(B1);
    {
      float e1[12];
      #pragma unroll
      for (int k = 0; k < 12; ++k) e1[k] = B1[k] + trg[k];
      PARTIALS_V(e1, 1);
      PUBLISH(tagV, 1, 1);
    }
    LOADROW(B0, 4);
    PIN12(B2);
    #pragma unroll
    for (int k = 0; k < 12; ++k) etrA[k] = B2[k] + trg[k];

    // loop t = 2..253 (63 quad blocks), then peel 254, 255
    #pragma unroll 1
    for (int m = 0; m < 63; ++m) {
      const int t0 = 4*m + 2;
      ITER_V(t0,     B1, B3, etrA, etrB);
      ITER_V(t0 + 1, B2, B0, etrB, etrA);
      ITER_V(t0 + 2, B3, B1, etrA, etrB);
      ITER_V(t0 + 3, B0, B2, etrB, etrA);
    }
    // t=254: pin row 255 (B3), merge 253, publish 254
    {
      PIN12(B3);
      #pragma unroll
      for (int k = 0; k < 12; ++k) etrB[k] = B3[k] + trg[k];
      MERGE_V(253);
      PARTIALS_V(etrA, 0);
      PUBLISH(tagV, 0, 254);
    }
    // t=255: merge 254, publish 255
    {
      MERGE_V(254);
      PARTIALS_V(etrB, 1);
      PUBLISH(tagV, 1, 255);
    }
    // final merge of step 255
    MERGE_V(255);
    if (tid == LEND) ws[BB + b] = vbest;  // best[END]
    __syncthreads();

    // ---- traceback, chunked (16 chunks x 16 steps) ----
    for (int idx = tid; idx < 16*LL; idx += 256) {
      int c = idx / LL, l = idx - c*LL;
      int pc = l;
      #pragma unroll
      for (int k = 15; k >= 0; --k) pc = bp[(16*c + k)*LL + pc];
      cmp_[c*LL + l] = (unsigned char)pc;
    }
    __syncthreads();
    if (tid == 0) {
      int pc = LEND;
      for (int c = 15; c >= 0; --c) { entry_[c] = (unsigned char)pc; pc = cmp_[c*LL + pc]; }
    }
    __syncthreads();
    if (tid < 16) {
      int c = tid, pc = entry_[c];
      #pragma unroll
      for (int k = 15; k >= 0; --k) { int t2 = 16*c + k; pc = bp[t2*LL + pc]; raw[t2] = (unsigned char)pc; }
    }
    __syncthreads();
    out[(size_t)b*TT + tid] = (tid < TT - 1) ? (float)raw[tid + 1] : (float)LEND;

  } else {
    // ===================== logsumexp (probability domain) =====================
    if ((tid & 63) == 0) {
      *(volatile int*)&tagS[0][w] = -1;
      *(volatile int*)&tagS[1][w] = -1;
    }
    __syncthreads();

    float trg2[12];
    #pragma unroll
    for (int k = 0; k < 12; ++k) trg2[k] = tr[(12*w + k)*LL + jl] * LOG2E;
    const float init = emB[LSTART*LL + jl] + tr[LSTART*LL + jl];
    const float m2 = RL(init, 0) * LOG2E;
    float P = act ? exp2f(init * LOG2E - m2) : 0.f;
    float macc = m2;

    float B0[12], B1[12], B2[12], B3[12], eeA[12], eeB[12];
    LOADROW(B1, 1); LOADROW(B2, 2); LOADROW(B3, 3);
    PIN12(B1);
    {
      float e1[12];
      #pragma unroll
      for (int k = 0; k < 12; ++k) e1[k] = exp2f(fmaf(B1[k], LOG2E, trg2[k]));
      PARTIALS_L(e1, 1);
      PUBLISH(tagS, 1, 1);
    }
    LOADROW(B0, 4);
    PIN12(B2);
    #pragma unroll
    for (int k = 0; k < 12; ++k) eeA[k] = exp2f(fmaf(B2[k], LOG2E, trg2[k]));

    #pragma unroll 1
    for (int m = 0; m < 63; ++m) {
      const int t0 = 4*m + 2;
      ITER_L(t0,     B1, B3, eeA, eeB);
      ITER_L(t0 + 1, B2, B0, eeB, eeA);
      ITER_L(t0 + 2, B3, B1, eeA, eeB);
      ITER_L(t0 + 3, B0, B2, eeB, eeA);
    }
    // t=254
    {
      PIN12(B3);
      #pragma unroll
      for (int k = 0; k < 12; ++k) eeB[k] = exp2f(fmaf(B3[k], LOG2E, trg2[k]));
      MERGE_L(253);
      PARTIALS_L(eeA, 0);
      PUBLISH(tagS, 0, 254);
    }
    // t=255
    {
      MERGE_L(254);
      PARTIALS_L(eeB, 1);
      PUBLISH(tagS, 1, 255);
    }
    MERGE_L(255);
    if (tid == LEND) ws[b] = (macc + __log2f(P)) * LN2;   // upto[END] in nats
  }
}

__global__ void viterbi_score(const float* __restrict__ ws, float* __restrict__ out)
{
  int b = threadIdx.x;
  if (b < BB) out[(size_t)BB*TT + b] = ws[BB + b] - ws[b];  // best - upto
}

extern "C" void kernel_launch(void* const* d_in, const int* in_sizes, int n_in,
                              void* d_out, int out_size, void* d_ws, size_t ws_size,
                              hipStream_t stream) {
  const float* em  = (const float*)d_in[0];
  const float* tr  = (const float*)d_in[1];
  const int*   ln  = (const int*)d_in[2];
  float* out = (float*)d_out;
  float* ws  = (float*)d_ws;
  viterbi_fwd<<<dim3(64), dim3(256), 0, stream>>>(em, tr, ln, out, ws);
  viterbi_score<<<dim3(1), dim3(64), 0, stream>>>(ws, out);
}